// Round 2
// baseline (803.582 us; speedup 1.0000x reference)
//
#include <hip/hip_runtime.h>

// ---------------------------------------------------------------------------
// ChemistryAwareDecoder on MI355X (gfx950)
// N=100000 nodes, E=200000 edges, SD=128, CD=768
// Fused block-diagonal GEMM [E x 896] @ [896 x 384], bf16x3 compensated MFMA.
// R2: compile-time phase split + early structural-acc retirement to cut peak
// register liveness -> 3 waves/SIMD (was 2, reg-capped at ~220 incl. AGPRs).
// ---------------------------------------------------------------------------

typedef float  f32x4  __attribute__((ext_vector_type(4)));
typedef __bf16 bf16x8 __attribute__((ext_vector_type(8)));
typedef __bf16 bf16x4 __attribute__((ext_vector_type(4)));

#define N_NODES 100000
#define E_EDGES 200000
#define KSTEPS  28                    // 896 / 32
#define NOUT    384                   // 64 + 192 + 128 fused outputs
#define PTOT    (KSTEPS * NOUT * 32)  // 344064 weight elements

// workspace layout (bytes)
#define WS_WHI   0
#define WS_WLO   688128
#define WS_B1    1376256
#define WS_W2    1377792
#define WS_CONST 1379328

__device__ __forceinline__ unsigned short f2bf(float f) {
  unsigned int x = __float_as_uint(f);
  unsigned int r = (x + 0x7FFFu + ((x >> 16) & 1u)) >> 16;  // RNE
  return (unsigned short)r;
}
__device__ __forceinline__ float bf2f(unsigned short u) {
  return __uint_as_float(((unsigned int)u) << 16);
}

// ---------------------------------------------------------------------------
// Prep: fused block-diagonal weight panels (pre-transposed, pre-split bf16
// hi/lo), fused bias/layer-2 vectors, softmax consts, edge-dtype detection.
// Panel: whi[p][n][kk], p = k/32, n = 0..383, kk = k%32.
// Wbig[k][n]: n<64: sw1 (k<128) | n<256: cw1 (k>=128) | n>=256: mw1 (all k)
// ---------------------------------------------------------------------------
__global__ __launch_bounds__(256) void prep_kernel(
    const float* __restrict__ sw1, const float* __restrict__ sb1,
    const float* __restrict__ sw2, const float* __restrict__ sb2,
    const float* __restrict__ cw1, const float* __restrict__ cb1,
    const float* __restrict__ cw2, const float* __restrict__ cb2,
    const float* __restrict__ mw1, const float* __restrict__ mb1,
    const float* __restrict__ mw2, const float* __restrict__ mb2,
    const float* __restrict__ pw,  const int* __restrict__ edge_i32,
    unsigned short* __restrict__ whi, unsigned short* __restrict__ wlo,
    float* __restrict__ b1cat, float* __restrict__ w2cat,
    float* __restrict__ consts)
{
  const int idx = blockIdx.x * 256 + threadIdx.x;
  if (idx < PTOT) {
    const int p  = idx / (NOUT * 32);
    const int r  = idx % (NOUT * 32);
    const int n  = r >> 5;
    const int kk = r & 31;
    const int k  = p * 32 + kk;
    float v;
    if (n < 64)       v = (k < 128)  ? sw1[k * 64 + n] : 0.0f;
    else if (n < 256) v = (k >= 128) ? cw1[(size_t)(k - 128) * 192 + (n - 64)] : 0.0f;
    else              v = mw1[(size_t)k * 128 + (n - 256)];
    const unsigned short hi = f2bf(v);
    const unsigned short lo = f2bf(v - bf2f(hi));
    whi[idx] = hi;
    wlo[idx] = lo;
  } else if (idx < PTOT + NOUT) {
    const int j = idx - PTOT;
    float b, w;
    if (j < 64)       { b = sb1[j];       w = sw2[j]; }
    else if (j < 256) { b = cb1[j - 64];  w = cw2[j - 64]; }
    else              { b = mb1[j - 256]; w = mw2[j - 256]; }
    b1cat[j] = b;
    w2cat[j] = w;
  } else if (idx == PTOT + NOUT) {
    const float p0 = pw[0], p1 = pw[1], p2 = pw[2];
    const float mx = fmaxf(p0, fmaxf(p1, p2));
    const float e0 = __expf(p0 - mx), e1 = __expf(p1 - mx), e2 = __expf(p2 - mx);
    const float inv = 1.0f / (e0 + e1 + e2);
    const float w0 = e0 * inv, w1 = e1 * inv, w2v = e2 * inv;
    consts[0] = w0; consts[1] = w1; consts[2] = w2v;
    consts[3] = w0 * sb2[0] + w1 * cb2[0] + w2v * mb2[0];  // valid-path bias
    consts[4] = sb2[0];                                    // invalid-path bias
    unsigned o = 0;
    for (int i = 0; i < 64; ++i) o |= (unsigned)edge_i32[2 * i + 1];
    consts[5] = (o == 0u) ? 1.0f : 0.0f;  // 1 => int64 edge layout
  }
}

#define MFMA3(A, AH, AL, BH, BL)                                          \
  A = __builtin_amdgcn_mfma_f32_16x16x32_bf16(AH, BH, A, 0, 0, 0);        \
  A = __builtin_amdgcn_mfma_f32_16x16x32_bf16(AH, BL, A, 0, 0, 0);        \
  A = __builtin_amdgcn_mfma_f32_16x16x32_bf16(AL, BH, A, 0, 0, 0);

// ---------------------------------------------------------------------------
// Main: 64 edges/block, 256 threads (4 waves).
// Wave wv tiles: S (ti=wv, struct, k<128 only), C0/C1 (ti=16/20+wv, combined,
// all k), H0..H2 (ti=4/8/12+wv, chemical, k>=128 only).
// Phase A (s=0..3): S,C0,C1 live (48 acc regs). S retired to scoreL at the
// boundary. Phase B (s=4..27): C0,C1,H0..H2 live (80 acc regs).
// __launch_bounds__(256,3): cap ~170 regs -> 12 waves/CU (was 8).
// ---------------------------------------------------------------------------
__global__ __launch_bounds__(256, 3) void decoder_main(
    const float* __restrict__ z, const float* __restrict__ chem,
    const int* __restrict__ edge, const int* __restrict__ mask,
    const unsigned short* __restrict__ whi, const unsigned short* __restrict__ wlo,
    const float* __restrict__ b1cat, const float* __restrict__ w2cat,
    const float* __restrict__ consts, float* __restrict__ out)
{
  __shared__ unsigned short Ah[2][64][40];  // stride 40: best 16B-aligned pad
  __shared__ unsigned short Al[2][64][40];
  __shared__ int   srcL[64];
  __shared__ int   dstL[64];
  __shared__ float validL[64];
  __shared__ float scoreL[64];

  const int tid  = threadIdx.x;
  const int lane = tid & 63;
  const int wv   = tid >> 6;
  const int li   = lane & 15;
  const int q    = lane >> 4;
  const int m0   = blockIdx.x << 6;

  if (tid < 64) {
    scoreL[tid] = 0.0f;
    const int e = m0 + tid;
    int s_, d_;
    if (consts[5] > 0.5f) { s_ = edge[4 * e]; d_ = edge[4 * e + 2]; }  // int64
    else                  { s_ = edge[2 * e]; d_ = edge[2 * e + 1]; }  // int32
    srcL[tid] = s_;
    dstL[tid] = d_;
    validL[tid] = (mask[s_] != 0 && mask[d_] != 0) ? 1.0f : 0.0f;
  }
  __syncthreads();

  // staging slots: thread handles rows mA, mB at k-quad kc
  const int mA = tid >> 3;
  const int mB = 32 + mA;
  const int kc = (tid & 7) << 2;
  const float* zsA = z + (size_t)srcL[mA] * 128 + kc;
  const float* zdA = z + (size_t)dstL[mA] * 128 + kc;
  const float* zsB = z + (size_t)srcL[mB] * 128 + kc;
  const float* zdB = z + (size_t)dstL[mB] * 128 + kc;
  const float* csA = chem + (size_t)srcL[mA] * 768 + kc;
  const float* cdA = chem + (size_t)dstL[mA] * 768 + kc;
  const float* csB = chem + (size_t)srcL[mB] * 768 + kc;
  const float* cdB = chem + (size_t)dstL[mB] * 768 + kc;

  auto split_store = [&](int buf, int m, f32x4 p) {
    bf16x4 h, l;
#pragma unroll
    for (int j = 0; j < 4; ++j) {
      const float pj = p[j];
      const __bf16 hb = (__bf16)pj;          // v_cvt RNE
      h[j] = hb;
      l[j] = (__bf16)(pj - (float)hb);
    }
    *(bf16x4*)&Ah[buf][m][kc] = h;
    *(bf16x4*)&Al[buf][m][kc] = l;
  };

  // stage step 0 (k0=0, from z)
  {
    const f32x4 a0 = *(const f32x4*)zsA;
    const f32x4 b0 = *(const f32x4*)zdA;
    const f32x4 a1 = *(const f32x4*)zsB;
    const f32x4 b1 = *(const f32x4*)zdB;
    split_store(0, mA, a0 * b0);
    split_store(0, mB, a1 * b1);
  }
  __syncthreads();

  // per-wave B column offsets (elements) within a k-panel
  const int colS  = ((wv)      * 16 + li) * 32 + q * 8;
  const int colC0 = ((16 + wv) * 16 + li) * 32 + q * 8;
  const int colC1 = ((20 + wv) * 16 + li) * 32 + q * 8;
  const int colH0 = ((4 + wv)  * 16 + li) * 32 + q * 8;
  const int colH1 = ((8 + wv)  * 16 + li) * 32 + q * 8;
  const int colH2 = ((12 + wv) * 16 + li) * 32 + q * 8;

  const float w0c = consts[0], w1c = consts[1], w2c = consts[2];

  f32x4 accS[4], accC0[4], accC1[4];
#pragma unroll
  for (int mt = 0; mt < 4; ++mt) {
    accS[mt] = (f32x4){0.f, 0.f, 0.f, 0.f};
    accC0[mt] = (f32x4){0.f, 0.f, 0.f, 0.f};
    accC1[mt] = (f32x4){0.f, 0.f, 0.f, 0.f};
  }

  // ---------------- phase A: s = 0..3 (structural k-range) ----------------
  for (int s = 0; s < 4; ++s) {
    const int buf = s & 1;
    bf16x8 afh[4], afl[4];
#pragma unroll
    for (int mt = 0; mt < 4; ++mt) {
      afh[mt] = *(const bf16x8*)&Ah[buf][mt * 16 + li][q * 8];
      afl[mt] = *(const bf16x8*)&Al[buf][mt * 16 + li][q * 8];
    }
    const unsigned short* wph = whi + (size_t)s * (NOUT * 32);
    const unsigned short* wpl = wlo + (size_t)s * (NOUT * 32);
    const bf16x8 bSh  = *(const bf16x8*)(wph + colS);
    const bf16x8 bSl  = *(const bf16x8*)(wpl + colS);
    const bf16x8 bC0h = *(const bf16x8*)(wph + colC0);
    const bf16x8 bC0l = *(const bf16x8*)(wpl + colC0);
    const bf16x8 bC1h = *(const bf16x8*)(wph + colC1);
    const bf16x8 bC1l = *(const bf16x8*)(wpl + colC1);

    // prefetch next A-tile gathers (consumed after MFMAs)
    f32x4 ga, gb, gc, gd;
    if (s < 3) {
      const int k0 = (s + 1) * 32;
      ga = *(const f32x4*)(zsA + k0); gb = *(const f32x4*)(zdA + k0);
      gc = *(const f32x4*)(zsB + k0); gd = *(const f32x4*)(zdB + k0);
    } else {
      ga = *(const f32x4*)csA; gb = *(const f32x4*)cdA;
      gc = *(const f32x4*)csB; gd = *(const f32x4*)cdB;
    }

#pragma unroll
    for (int mt = 0; mt < 4; ++mt) {
      MFMA3(accS[mt],  afh[mt], afl[mt], bSh,  bSl);
      MFMA3(accC0[mt], afh[mt], afl[mt], bC0h, bC0l);
      MFMA3(accC1[mt], afh[mt], afl[mt], bC1h, bC1l);
    }

    const int nb = buf ^ 1;
    split_store(nb, mA, ga * gb);
    split_store(nb, mB, gc * gd);
    __syncthreads();
  }

  // retire structural tile now (its K-range is done) -> frees 16 regs
  {
    const int col = wv * 16 + li;
    const float b1 = b1cat[col];
    const float w2 = w2cat[col];
#pragma unroll
    for (int mt = 0; mt < 4; ++mt) {
#pragma unroll
      for (int r = 0; r < 4; ++r) {
        const float valid = validL[mt * 16 + q * 4 + r];
        const float a = 1.0f + valid * (w0c - 1.0f);  // valid ? w0 : 1
        float v = fmaxf(accS[mt][r] + b1, 0.0f);
        v = a * v * w2;
        v += __shfl_xor(v, 1);
        v += __shfl_xor(v, 2);
        v += __shfl_xor(v, 4);
        v += __shfl_xor(v, 8);
        if (li == 0) atomicAdd(&scoreL[mt * 16 + q * 4 + r], v);
      }
    }
  }

  // ---------------- phase B: s = 4..27 (chemical k-range) ----------------
  f32x4 accH0[4], accH1[4], accH2[4];
#pragma unroll
  for (int mt = 0; mt < 4; ++mt) {
    accH0[mt] = (f32x4){0.f, 0.f, 0.f, 0.f};
    accH1[mt] = (f32x4){0.f, 0.f, 0.f, 0.f};
    accH2[mt] = (f32x4){0.f, 0.f, 0.f, 0.f};
  }

  for (int s = 4; s < KSTEPS; ++s) {
    const int buf = s & 1;
    bf16x8 afh[4], afl[4];
#pragma unroll
    for (int mt = 0; mt < 4; ++mt) {
      afh[mt] = *(const bf16x8*)&Ah[buf][mt * 16 + li][q * 8];
      afl[mt] = *(const bf16x8*)&Al[buf][mt * 16 + li][q * 8];
    }
    const unsigned short* wph = whi + (size_t)s * (NOUT * 32);
    const unsigned short* wpl = wlo + (size_t)s * (NOUT * 32);
    const bf16x8 bC0h = *(const bf16x8*)(wph + colC0);
    const bf16x8 bC0l = *(const bf16x8*)(wpl + colC0);
    const bf16x8 bC1h = *(const bf16x8*)(wph + colC1);
    const bf16x8 bC1l = *(const bf16x8*)(wpl + colC1);
    const bf16x8 bH0h = *(const bf16x8*)(wph + colH0);
    const bf16x8 bH0l = *(const bf16x8*)(wpl + colH0);
    const bf16x8 bH1h = *(const bf16x8*)(wph + colH1);
    const bf16x8 bH1l = *(const bf16x8*)(wpl + colH1);
    const bf16x8 bH2h = *(const bf16x8*)(wph + colH2);
    const bf16x8 bH2l = *(const bf16x8*)(wpl + colH2);

    f32x4 ga, gb, gc, gd;
    const bool hn = (s + 1 < KSTEPS);
    if (hn) {
      const int ko = (s + 1) * 32 - 128;
      ga = *(const f32x4*)(csA + ko); gb = *(const f32x4*)(cdA + ko);
      gc = *(const f32x4*)(csB + ko); gd = *(const f32x4*)(cdB + ko);
    }

#pragma unroll
    for (int mt = 0; mt < 4; ++mt) {
      MFMA3(accH0[mt], afh[mt], afl[mt], bH0h, bH0l);
      MFMA3(accH1[mt], afh[mt], afl[mt], bH1h, bH1l);
      MFMA3(accH2[mt], afh[mt], afl[mt], bH2h, bH2l);
      MFMA3(accC0[mt], afh[mt], afl[mt], bC0h, bC0l);
      MFMA3(accC1[mt], afh[mt], afl[mt], bC1h, bC1l);
    }

    if (hn) {
      const int nb = buf ^ 1;
      split_store(nb, mA, ga * gb);
      split_store(nb, mB, gc * gd);
    }
    __syncthreads();
  }

  // ---------------- epilogue: C0, C1 (combined), H0..H2 (chemical) --------
  {
    float part[4][4];
#pragma unroll
    for (int mt = 0; mt < 4; ++mt)
#pragma unroll
      for (int r = 0; r < 4; ++r) part[mt][r] = 0.f;

#define ACCUM_TILE(ACC, TI, WP)                                     \
    {                                                               \
      const int col = (TI) * 16 + li;                               \
      const float b1 = b1cat[col];                                  \
      const float w2 = w2cat[col];                                  \
      _Pragma("unroll")                                             \
      for (int mt = 0; mt < 4; ++mt) {                              \
        _Pragma("unroll")                                           \
        for (int r = 0; r < 4; ++r) {                               \
          const float valid = validL[mt * 16 + q * 4 + r];          \
          const float a = valid * (WP);                             \
          float v = fmaxf(ACC[mt][r] + b1, 0.0f);                   \
          part[mt][r] += a * v * w2;                                \
        }                                                           \
      }                                                             \
    }

    ACCUM_TILE(accC0, 16 + wv, w2c)
    ACCUM_TILE(accC1, 20 + wv, w2c)
    ACCUM_TILE(accH0, 4 + wv,  w1c)
    ACCUM_TILE(accH1, 8 + wv,  w1c)
    ACCUM_TILE(accH2, 12 + wv, w1c)
#undef ACCUM_TILE

#pragma unroll
    for (int mt = 0; mt < 4; ++mt) {
#pragma unroll
      for (int r = 0; r < 4; ++r) {
        float v = part[mt][r];
        v += __shfl_xor(v, 1);
        v += __shfl_xor(v, 2);
        v += __shfl_xor(v, 4);
        v += __shfl_xor(v, 8);
        if (li == 0) atomicAdd(&scoreL[mt * 16 + q * 4 + r], v);
      }
    }
  }
  __syncthreads();

  if (tid < 64) {
    const float valid = validL[tid];
    const float cadd = consts[4] + valid * (consts[3] - consts[4]);
    out[m0 + tid] = scoreL[tid] + cadd;
  }
}

// ---------------------------------------------------------------------------
extern "C" void kernel_launch(void* const* d_in, const int* in_sizes, int n_in,
                              void* d_out, int out_size, void* d_ws, size_t ws_size,
                              hipStream_t stream)
{
  const float* z    = (const float*)d_in[0];
  const float* chem = (const float*)d_in[1];
  const int*   edge = (const int*)d_in[2];
  const int*   mask = (const int*)d_in[3];
  const float* sw1  = (const float*)d_in[4];
  const float* sb1  = (const float*)d_in[5];
  const float* sw2  = (const float*)d_in[6];
  const float* sb2  = (const float*)d_in[7];
  const float* cw1  = (const float*)d_in[8];
  const float* cb1  = (const float*)d_in[9];
  const float* cw2  = (const float*)d_in[10];
  const float* cb2  = (const float*)d_in[11];
  const float* mw1  = (const float*)d_in[12];
  const float* mb1  = (const float*)d_in[13];
  const float* mw2  = (const float*)d_in[14];
  const float* mb2  = (const float*)d_in[15];
  const float* pw   = (const float*)d_in[16];

  char* ws = (char*)d_ws;
  unsigned short* whi = (unsigned short*)(ws + WS_WHI);
  unsigned short* wlo = (unsigned short*)(ws + WS_WLO);
  float* b1cat  = (float*)(ws + WS_B1);
  float* w2cat  = (float*)(ws + WS_W2);
  float* consts = (float*)(ws + WS_CONST);

  const int prep_tasks  = PTOT + NOUT + 64;
  const int prep_blocks = (prep_tasks + 255) / 256;
  prep_kernel<<<prep_blocks, 256, 0, stream>>>(
      sw1, sb1, sw2, sb2, cw1, cb1, cw2, cb2, mw1, mb1, mw2, mb2, pw, edge,
      whi, wlo, b1cat, w2cat, consts);

  decoder_main<<<E_EDGES / 64, 256, 0, stream>>>(
      z, chem, edge, mask, whi, wlo, b1cat, w2cat, consts, (float*)d_out);
}